// Round 2
// baseline (206.761 us; speedup 1.0000x reference)
//
#include <hip/hip_runtime.h>
#include <hip/hip_bf16.h>
#include <stdint.h>

typedef __attribute__((ext_vector_type(4))) float          f32x4;
typedef __attribute__((ext_vector_type(4))) float          f4;
typedef __attribute__((ext_vector_type(2))) unsigned int   u32x2;
typedef __bf16 bf16_t;
typedef __attribute__((ext_vector_type(8))) bf16_t         bf16x8;
typedef __attribute__((ext_vector_type(8))) unsigned short u16x8;

#define NB 2
#define NS 4096
#define ND 768
#define NH 12
#define NW 256

__device__ __forceinline__ unsigned short f2bf(float f) {
  union { float f; unsigned u; } v; v.f = f;
  unsigned r = v.u + 0x7fffu + ((v.u >> 16) & 1u);
  return (unsigned short)(r >> 16);
}

__device__ __forceinline__ void gload16(const void* g, void* l) {
  __builtin_amdgcn_global_load_lds((const __attribute__((address_space(1))) void*)g,
                                   (__attribute__((address_space(3))) void*)l, 16, 0, 0);
}

// ---------------- f32 -> bf16 cast ----------------
__global__ void cast_kernel(const float* __restrict__ in, unsigned short* __restrict__ out, int n4) {
  int i = blockIdx.x * blockDim.x + threadIdx.x;
  int stride = gridDim.x * blockDim.x;
  for (; i < n4; i += stride) {
    f4 v = reinterpret_cast<const f4*>(in)[i];
    unsigned u0 = (unsigned)f2bf(v.x) | ((unsigned)f2bf(v.y) << 16);
    unsigned u1 = (unsigned)f2bf(v.z) | ((unsigned)f2bf(v.w) << 16);
    u32x2 o = {u0, u1};
    reinterpret_cast<u32x2*>(out)[i] = o;
  }
}

// ---------------- fused QKV projection GEMM ----------------
// C[i,j] = sum_k A[i,k] * W[j,k]   (A: 8192x768 bf16, W rows: 768x768 bf16)
__global__ __launch_bounds__(256) void qkv_gemm(
    const unsigned short* __restrict__ Ab,
    const unsigned short* __restrict__ Wqb,
    const unsigned short* __restrict__ Wkb,
    const unsigned short* __restrict__ Wvb,
    const float* __restrict__ bqp, const float* __restrict__ bkp, const float* __restrict__ bvp,
    unsigned short* __restrict__ Qw, unsigned short* __restrict__ Kw, unsigned short* __restrict__ Vw) {
  __shared__ unsigned short As[128 * 32];
  __shared__ unsigned short Bs[128 * 32];

  int bid = blockIdx.x;
  int bn = bid % 18, bm = bid / 18;
  int mat = bn / 6, bnn = bn % 6;
  const unsigned short* Wm = (mat == 0) ? Wqb : ((mat == 1) ? Wkb : Wvb);
  const float* bias = (mat == 0) ? bqp : ((mat == 1) ? bkp : bvp);
  unsigned short* dst = (mat == 0) ? Qw : ((mat == 1) ? Kw : Vw);

  int t = threadIdx.x;
  int w = t >> 6, l = t & 63;
  int lg = l >> 4, ln = l & 15;
  int wm = w & 1, wn = w >> 1;

  f32x4 acc[4][4];
#pragma unroll
  for (int i = 0; i < 4; i++)
#pragma unroll
    for (int j = 0; j < 4; j++) acc[i][j] = f32x4{0.f, 0.f, 0.f, 0.f};

  for (int kt = 0; kt < 24; ++kt) {
    __syncthreads();
#pragma unroll
    for (int is = 0; is < 2; ++is) {
      int chunk = is * 256 + t;       // 0..511, 16B each
      int row = chunk >> 2;           // 0..127
      int c8 = (chunk & 3) * 8;       // elem offset in 32-wide k-slice
      gload16(Ab + ((size_t)(bm * 128 + row)) * 768 + kt * 32 + c8, As + chunk * 8);
      gload16(Wm + ((size_t)(bnn * 128 + row)) * 768 + kt * 32 + c8, Bs + chunk * 8);
    }
    __syncthreads();
    bf16x8 af[4], bfr[4];
#pragma unroll
    for (int i = 0; i < 4; i++) {
      af[i]  = *reinterpret_cast<const bf16x8*>(As + (wm * 64 + i * 16 + ln) * 32 + lg * 8);
      bfr[i] = *reinterpret_cast<const bf16x8*>(Bs + (wn * 64 + i * 16 + ln) * 32 + lg * 8);
    }
#pragma unroll
    for (int i = 0; i < 4; i++)
#pragma unroll
      for (int j = 0; j < 4; j++)
        acc[i][j] = __builtin_amdgcn_mfma_f32_16x16x32_bf16(af[i], bfr[j], acc[i][j], 0, 0, 0);
  }

  // epilogue: bias (+ 1/8 scale for Q), convert, scatter to (B,H,S,64)
#pragma unroll
  for (int j = 0; j < 4; j++) {
    int col = bnn * 128 + wn * 64 + j * 16 + ln;  // within-matrix column 0..767
    float bv_ = bias[col];
    int hh = col >> 6, dd = col & 63;
#pragma unroll
    for (int i = 0; i < 4; i++) {
#pragma unroll
      for (int r = 0; r < 4; r++) {
        int tok = bm * 128 + wm * 64 + i * 16 + lg * 4 + r;
        int bb = tok >> 12, ss = tok & 4095;
        float v = acc[i][j][r] + bv_;
        if (mat == 0) v *= 0.125f;
        dst[(((size_t)bb * 12 + hh) * 4096 + ss) * 64 + dd] = f2bf(v);
      }
    }
  }
}

// ---------------- fused band + global attention ----------------
// 1 block = (b,h, 64-query chunk). 4 waves x 16 query rows each.
__global__ __launch_bounds__(256) void attn_kernel(
    const unsigned short* __restrict__ Qw,
    const unsigned short* __restrict__ Kw,
    const unsigned short* __restrict__ Vw,
    const int* __restrict__ amask,
    float* __restrict__ out) {
  __shared__ unsigned short Ks[64 * 64];      // [key][d], XOR-swizzled granules within row
  __shared__ unsigned short Vt[64 * 64];      // [d][key] transposed, XOR-swizzled within row
  __shared__ unsigned short Ps[4][16 * 72];   // per-wave P bounce, padded rows

  int bid = blockIdx.x;
  int qc = bid & 63;
  int bh = bid >> 6;       // 0..23
  int b = bh / 12;
  int hh = bh % 12;
  int qbase = qc * 64;

  int t = threadIdx.x, w = t >> 6, l = t & 63;
  int lg = l >> 4, ln = l & 15;

  const unsigned short* Qbh = Qw + (size_t)bh * (NS * 64);
  const unsigned short* Kbh = Kw + (size_t)bh * (NS * 64);
  const unsigned short* Vbh = Vw + (size_t)bh * (NS * 64);
  const int* mrow = amask + b * NS;

  // Q fragments in registers for the whole kernel (A-frag row m = ln -> q = qbase+w*16+ln)
  bf16x8 qf[2];
  {
    const unsigned short* qp = Qbh + (size_t)(qbase + w * 16 + ln) * 64 + lg * 8;
    qf[0] = *reinterpret_cast<const bf16x8*>(qp);
    qf[1] = *reinterpret_cast<const bf16x8*>(qp + 32);
  }

  float m_r[4] = {-1e30f, -1e30f, -1e30f, -1e30f};
  float l_r[4] = {0.f, 0.f, 0.f, 0.f};
  f32x4 oacc[4];
#pragma unroll
  for (int i = 0; i < 4; i++) oacc[i] = f32x4{0.f, 0.f, 0.f, 0.f};

  int q0 = qbase + w * 16 + lg * 4;

  // tt = -1: global tile (keys 0..63, unmasked). tt 0..8: band tiles.
  for (int tt = -1; tt < 9; ++tt) {
    int key0 = (tt < 0) ? 0 : (qbase - 256 + tt * 64);
    if (key0 < 0 || key0 >= NS) continue;  // uniform across block

    __syncthreads();
    // --- K stage: global_load_lds, source pre-swizzled so swizzled reads round-trip
#pragma unroll
    for (int is = 0; is < 2; ++is) {
      int chunk = is * 256 + t;           // 16B granules; LDS dest = linear lane order
      int krow = chunk >> 3, gran = chunk & 7;
      gload16(Kbh + (size_t)(key0 + krow) * 64 + (gran ^ (krow & 7)) * 8, Ks + chunk * 8);
    }
    // --- V stage: reg-load rows, write transposed+swizzled: element e of row d holds key e^((d&7)<<3)
    u16x8 vv[2];
#pragma unroll
    for (int is = 0; is < 2; ++is) {
      int g = is * 256 + t;
      int key = g & 63, d0 = (g >> 6) * 8;  // lanes -> consecutive keys
      vv[is] = *reinterpret_cast<const u16x8*>(Vbh + (size_t)(key0 + key) * 64 + d0);
    }
#pragma unroll
    for (int is = 0; is < 2; ++is) {
      int g = is * 256 + t;
      int key = g & 63, d0 = (g >> 6) * 8;
#pragma unroll
      for (int j = 0; j < 8; ++j) {
        int d = d0 + j;
        Vt[d * 64 + (key ^ ((d & 7) << 3))] = vv[is][j];
      }
    }
    __syncthreads();

    // --- QK^T: S[q][key], D-row = lg*4+r, D-col = nt*16+ln
    f32x4 sa[4];
#pragma unroll
    for (int nt = 0; nt < 4; nt++) sa[nt] = f32x4{0.f, 0.f, 0.f, 0.f};
#pragma unroll
    for (int nt = 0; nt < 4; nt++) {
      int key = nt * 16 + ln;
#pragma unroll
      for (int ks = 0; ks < 2; ++ks) {
        int dby = (ks * 64 + lg * 16) ^ ((key & 7) << 4);
        bf16x8 kf = *reinterpret_cast<const bf16x8*>(Ks + key * 64 + (dby >> 1));
        sa[nt] = __builtin_amdgcn_mfma_f32_16x16x32_bf16(qf[ks], kf, sa[nt], 0, 0, 0);
      }
    }

    // --- masking (band tiles only)
    if (tt >= 0) {
#pragma unroll
      for (int nt = 0; nt < 4; nt++) {
        int ka = key0 + nt * 16 + ln;
        int sup = mrow[ka];
#pragma unroll
        for (int r = 0; r < 4; r++) {
          int qa = q0 + r;
          bool ok = (sup == 0) && (ka >= qa - NW) && (ka <= qa + NW);
          if (!ok) sa[nt][r] = -1e30f;
        }
      }
    }

    // --- online softmax (row = lg group; reduce 4 nt in-lane + 16 lanes via shfl)
    float scl[4];
#pragma unroll
    for (int r = 0; r < 4; r++) {
      float v = fmaxf(fmaxf(sa[0][r], sa[1][r]), fmaxf(sa[2][r], sa[3][r]));
      v = fmaxf(v, __shfl_xor(v, 1, 64));
      v = fmaxf(v, __shfl_xor(v, 2, 64));
      v = fmaxf(v, __shfl_xor(v, 4, 64));
      v = fmaxf(v, __shfl_xor(v, 8, 64));
      float mn = fmaxf(m_r[r], v);
      scl[r] = __expf(m_r[r] - mn);
      m_r[r] = mn;
    }
#pragma unroll
    for (int r = 0; r < 4; r++) {
      float s = 0.f;
#pragma unroll
      for (int nt = 0; nt < 4; nt++) {
        float p = __expf(sa[nt][r] - m_r[r]);
        sa[nt][r] = p;
        s += p;
      }
      s += __shfl_xor(s, 1, 64);
      s += __shfl_xor(s, 2, 64);
      s += __shfl_xor(s, 4, 64);
      s += __shfl_xor(s, 8, 64);
      l_r[r] = l_r[r] * scl[r] + s;
    }
#pragma unroll
    for (int nt = 0; nt < 4; nt++)
#pragma unroll
      for (int r = 0; r < 4; r++) oacc[nt][r] *= scl[r];

    // --- P -> bf16 -> per-wave LDS bounce (row = q within wave, col = key)
    unsigned short* pw = &Ps[w][0];
#pragma unroll
    for (int nt = 0; nt < 4; nt++)
#pragma unroll
      for (int r = 0; r < 4; r++)
        pw[(lg * 4 + r) * 72 + nt * 16 + ln] = f2bf(sa[nt][r]);

    // --- PV: O[q][d] += P[q][keys] @ V[keys][d], V^T read with matching swizzle
#pragma unroll
    for (int ks = 0; ks < 2; ++ks) {
      bf16x8 pf = *reinterpret_cast<const bf16x8*>(pw + ln * 72 + ks * 32 + lg * 8);
#pragma unroll
      for (int nt = 0; nt < 4; ++nt) {
        int d = nt * 16 + ln;
        int eoff = (ks * 32 + lg * 8) ^ ((d & 7) << 3);  // returns keys ks*32+lg*8 .. +7
        bf16x8 vf = *reinterpret_cast<const bf16x8*>(Vt + d * 64 + eoff);
        oacc[nt] = __builtin_amdgcn_mfma_f32_16x16x32_bf16(pf, vf, oacc[nt], 0, 0, 0);
      }
    }
  }

  // --- normalize + write out[(qa*B + b)*768 + h*64 + d] (f32)
#pragma unroll
  for (int nt = 0; nt < 4; nt++) {
    int d = nt * 16 + ln;
#pragma unroll
    for (int r = 0; r < 4; r++) {
      int qa = q0 + r;
      out[((size_t)qa * NB + b) * ND + hh * 64 + d] = oacc[nt][r] / l_r[r];
    }
  }
}

extern "C" void kernel_launch(void* const* d_in, const int* in_sizes, int n_in,
                              void* d_out, int out_size, void* d_ws, size_t ws_size,
                              hipStream_t stream) {
  (void)in_sizes; (void)n_in; (void)out_size; (void)ws_size;
  const float* hidden = (const float*)d_in[0];
  const int*   amask  = (const int*)d_in[1];
  const float* Wq = (const float*)d_in[2];
  const float* bq = (const float*)d_in[3];
  const float* Wk = (const float*)d_in[4];
  const float* bk = (const float*)d_in[5];
  const float* Wv = (const float*)d_in[6];
  const float* bv = (const float*)d_in[7];
  float* out = (float*)d_out;

  char* p = (char*)d_ws;
  unsigned short* hb  = (unsigned short*)p; p += (size_t)8192 * 768 * 2;
  unsigned short* wqb = (unsigned short*)p; p += (size_t)768 * 768 * 2;
  unsigned short* wkb = (unsigned short*)p; p += (size_t)768 * 768 * 2;
  unsigned short* wvb = (unsigned short*)p; p += (size_t)768 * 768 * 2;
  unsigned short* Qws = (unsigned short*)p; p += (size_t)24 * 4096 * 64 * 2;
  unsigned short* Kws = (unsigned short*)p; p += (size_t)24 * 4096 * 64 * 2;
  unsigned short* Vws = (unsigned short*)p; p += (size_t)24 * 4096 * 64 * 2;

  cast_kernel<<<1024, 256, 0, stream>>>(hidden, hb, 8192 * 768 / 4);
  cast_kernel<<<576, 256, 0, stream>>>(Wq, wqb, 768 * 768 / 4);
  cast_kernel<<<576, 256, 0, stream>>>(Wk, wkb, 768 * 768 / 4);
  cast_kernel<<<576, 256, 0, stream>>>(Wv, wvb, 768 * 768 / 4);
  qkv_gemm<<<64 * 18, 256, 0, stream>>>(hb, wqb, wkb, wvb, bq, bk, bv, Qws, Kws, Vws);
  attn_kernel<<<24 * 64, 256, 0, stream>>>(Qws, Kws, Vws, amask, out);
}